// Round 1
// 846.757 us; speedup vs baseline: 1.0802x; 1.0802x over previous
//
#include <hip/hip_runtime.h>

typedef _Float16 f16x8 __attribute__((ext_vector_type(8)));
typedef float    f32x4 __attribute__((ext_vector_type(4)));

constexpr int Nn = 32, Cc = 256, HW = 1024, Mm = 2000, Tt = 32768;
constexpr int TB = 16;        // tokens per block
constexpr int XROW = 264;     // X row stride (f16): 528 B rows, 16B-aligned
constexpr int YROW = 257;     // y accum row stride (fp32)
constexpr int LCAP = 512;     // candidate cap (expected ~109/block, 38 sigma margin)
constexpr float LAMBDA = 0.0025f;
constexpr float PLO = LAMBDA * (1.0f - 3e-3f);   // borderline window (covers all GEMM noise)
constexpr float PHI = LAMBDA * (1.0f + 3e-3f);
constexpr float ECUT = 4.8f;  // candidate cut: survivor needs e > lambda*Z >= 5.9 unless Z < 1920 (13 sigma)
constexpr float SCL = 4096.0f, ISCL = 1.0f / 4096.0f;

__global__ void wcvt_kernel(const float* __restrict__ w,
                            _Float16* __restrict__ whi, _Float16* __restrict__ wlo) {
  int i = blockIdx.x * 256 + threadIdx.x;
  if (i < Mm * Cc) {
    float v = w[i];
    _Float16 h = (_Float16)v;
    whi[i] = h;
    wlo[i] = (_Float16)((v - (float)h) * SCL);
  }
}

// launch_bounds (256,2): B double-buffer needs ~128 VGPRs on top of the
// hoisted A fragments (64) + accumulators; (256,3)'s 170-reg budget forces
// the compiler to drop prefetch and serialize every B load (R0: ~1000 cyc
// exposed latency per load -> 640 us with all pipes <7% busy).
__global__ __launch_bounds__(256, 2)
void fused_mem_kernel(const float* __restrict__ x, const float* __restrict__ wgt,
                      const _Float16* __restrict__ whi, const _Float16* __restrict__ wlo,
                      float* __restrict__ y_out, float* __restrict__ att_out) {
  // region B: Xh|Xl f16[16][264] x2 = 16896 B during GEMM1; yL f32[16][257] = 16448 B after
  __shared__ float bufB[TB * XROW];        // 16896 B (floats for alignment)
  __shared__ int   lm[LCAP];
  __shared__ float le[LCAP];
  __shared__ float la[LCAP];
  __shared__ float Zred[64];
  __shared__ float invZ[TB];
  __shared__ float l1s[TB];
  __shared__ float dens[TB];
  __shared__ int   lcnt;
  _Float16* Xh = (_Float16*)bufB;
  _Float16* Xl = Xh + TB * XROW;
  float*    yL = bufB;

  const int tid = threadIdx.x;
  const int wv  = tid >> 6;
  const int l   = tid & 63;
  const int qw  = l >> 4;
  const int lr  = l & 15;
  const int t0  = blockIdx.x * TB;
  const int n   = t0 >> 10;
  const int hw0 = t0 & 1023;

  if (tid == 0) lcnt = 0;
  if (tid < TB) l1s[tid] = 0.f;

  // ---- phase 1: X tile -> LDS f16 hi/lo ----
  {
    const int h = tid & 15, cb = tid >> 4;
    const float* xp = x + ((size_t)n * Cc) * HW + hw0 + h;
    #pragma unroll
    for (int j = 0; j < 16; ++j) {
      int c = cb * 16 + j;
      float v = xp[(size_t)c * HW];                 // 16 lanes consecutive: full 64B lines
      _Float16 hh = (_Float16)v;
      Xh[h * XROW + c] = hh;
      Xl[h * XROW + c] = (_Float16)((v - (float)hh) * SCL);
    }
  }
  __syncthreads();                                  // B1

  // ---- phase 2: GEMM1 via f16-split MFMA; exp fp32; candidates -> LDS list ----
  // Explicit mt-granularity register double-buffer for B: loads for tile mt+1
  // fly while tile mt's 24 MFMAs + epilogue execute. Accumulation order of
  // zp / logits is IDENTICAL to the previous passing kernel (numerics-safe:
  // the borderline lambda-threshold classification depends on Z bits).
  f16x8 ahi[8], alo[8];
  #pragma unroll
  for (int ks = 0; ks < 8; ++ks) {
    ahi[ks] = *(const f16x8*)&Xh[lr * XROW + ks * 32 + qw * 8];   // A[t=lane&15][k=qw*8+j]
    alo[ks] = *(const f16x8*)&Xl[lr * XROW + ks * 32 + qw * 8];
  }

  float zp[4] = {0.f, 0.f, 0.f, 0.f};
  const int strip = wv * 512;
  const int ntiles = (wv == 3) ? 29 : 32;           // 125 valid 16-row tiles; all mrow < 2000

#define LOADB(BH, BL, MT) do {                                                  \
    const _Float16* ph_ = whi + (size_t)(strip + (MT) * 16 + lr) * Cc + qw * 8; \
    const _Float16* pl_ = wlo + (size_t)(strip + (MT) * 16 + lr) * Cc + qw * 8; \
    _Pragma("unroll")                                                           \
    for (int ks = 0; ks < 8; ++ks) {                                            \
      BH[ks] = *(const f16x8*)(ph_ + ks * 32);      /* 16 full 64B lines */     \
      BL[ks] = *(const f16x8*)(pl_ + ks * 32);                                  \
    }                                                                           \
  } while (0)

#define COMPUTEB(BH, BL, MT) do {                                               \
    f32x4 ahh = {0.f, 0.f, 0.f, 0.f};                                           \
    f32x4 axl = {0.f, 0.f, 0.f, 0.f};                                           \
    f32x4 alh = {0.f, 0.f, 0.f, 0.f};               /* 3 independent 8-chains */\
    _Pragma("unroll")                                                           \
    for (int ks = 0; ks < 8; ++ks) {                                            \
      ahh = __builtin_amdgcn_mfma_f32_16x16x32_f16(ahi[ks], BH[ks], ahh, 0, 0, 0); \
      axl = __builtin_amdgcn_mfma_f32_16x16x32_f16(ahi[ks], BL[ks], axl, 0, 0, 0); \
      alh = __builtin_amdgcn_mfma_f32_16x16x32_f16(alo[ks], BH[ks], alh, 0, 0, 0); \
    }                                                                           \
    const int mrow_ = strip + (MT) * 16 + lr;                                   \
    _Pragma("unroll")                                                           \
    for (int r = 0; r < 4; ++r) {                                               \
      float s = fmaf(axl[r] + alh[r], ISCL, ahh[r]);   /* logit, ~fp32 accuracy */ \
      float e = __expf(s);                              /* |s| small: no max-subtract */ \
      zp[r] += e;                                                               \
      if (e > ECUT) {                                   /* ~0.3% taken */       \
        int slot = atomicAdd(&lcnt, 1);                                         \
        if (slot < LCAP) { lm[slot] = ((qw * 4 + r) << 16) | mrow_; le[slot] = e; } \
      }                                                                         \
    }                                                                           \
  } while (0)

  {
    f16x8 b0h[8], b0l[8], b1h[8], b1l[8];
    LOADB(b0h, b0l, 0);
    int mt = 0;
    for (;;) {
      if (mt + 1 < ntiles) LOADB(b1h, b1l, mt + 1);   // prefetch while computing b0
      COMPUTEB(b0h, b0l, mt);
      if (++mt == ntiles) break;
      if (mt + 1 < ntiles) LOADB(b0h, b0l, mt + 1);   // prefetch while computing b1
      COMPUTEB(b1h, b1l, mt);
      if (++mt == ntiles) break;
    }
  }
#undef LOADB
#undef COMPUTEB

  #pragma unroll
  for (int o = 1; o < 16; o <<= 1)
    #pragma unroll
    for (int r = 0; r < 4; ++r) zp[r] += __shfl_xor(zp[r], o);
  if (lr == 0) {
    #pragma unroll
    for (int r = 0; r < 4; ++r) Zred[wv * 16 + qw * 4 + r] = zp[r];
  }
  __syncthreads();                                  // B2

  if (tid < TB)
    invZ[tid] = 1.f / (Zred[0 * 16 + tid] + Zred[1 * 16 + tid] + Zred[2 * 16 + tid] + Zred[3 * 16 + tid]);
  __syncthreads();                                  // B3

  // ---- phase 4: candidate scan (exact fp32 recompute of borderline) + L1 ----
  const int ne = min(lcnt, LCAP);
  for (int e = tid; e < ne; e += 256) {
    const int tm = lm[e];
    const int t = tm >> 16, m = tm & 0xFFFF;
    float p = le[e] * invZ[t];
    float a = 0.f;
    if (p > PLO) {
      float pu = p;
      if (p < PHI) {
        // borderline (~1 per block): exact fp32 dot from global x, W
        const float* xr = x + ((size_t)n * Cc) * HW + hw0 + t;
        const float* wr = wgt + (size_t)m * Cc;
        float s = 0.f;
        for (int c = 0; c < Cc; ++c) s = fmaf(xr[(size_t)c * HW], wr[c], s);
        pu = expf(s) * invZ[t];
      }
      float d = pu - LAMBDA;
      if (d > 0.f) {
        a = (d * pu) / (d + 1e-12f);
        atomicAdd(&l1s[t], a);
      }
    }
    la[e] = a;
  }
  __syncthreads();                                  // B4

  if (tid < TB) dens[tid] = fmaxf(l1s[tid], 1e-12f);
  for (int i = tid; i < TB * YROW; i += 256) yL[i] = 0.f;   // X dead; alias reuse
  __syncthreads();                                  // B5

  // ---- phase 6: sparse GEMM2 from survivor list (fp32 W) + att scatter ----
  for (int e = wv; e < ne; e += 4) {                // wave-uniform entry -> no divergence
    float av = la[e];
    if (av > 0.f) {
      const int tm = lm[e];
      const int t = tm >> 16, m = tm & 0xFFFF;
      const float a = av / dens[t];
      float4 wf = *(const float4*)(wgt + (size_t)m * Cc + l * 4);
      atomicAdd(&yL[t * YROW + l * 4 + 0], a * wf.x);
      atomicAdd(&yL[t * YROW + l * 4 + 1], a * wf.y);
      atomicAdd(&yL[t * YROW + l * 4 + 2], a * wf.z);
      atomicAdd(&yL[t * YROW + l * 4 + 3], a * wf.w);
      if (l == 0)
        att_out[((size_t)(n * Mm + m)) * HW + hw0 + t] = a;   // bg pre-zeroed by memset dispatch
    }
  }
  __syncthreads();                                  // B6

  // ---- phase 7: y write (64B chunks: 16 consecutive hw per c) ----
  {
    const int h = tid & 15, cb = tid >> 4;
    float* yp = y_out + ((size_t)n * Cc) * HW + hw0 + h;
    #pragma unroll
    for (int j = 0; j < 16; ++j) {
      int c = cb * 16 + j;
      yp[(size_t)c * HW] = yL[h * YROW + c];
    }
  }
}

extern "C" void kernel_launch(void* const* d_in, const int* in_sizes, int n_in,
                              void* d_out, int out_size, void* d_ws, size_t ws_size,
                              hipStream_t stream) {
  const float* x = (const float*)d_in[0];
  const float* w = (const float*)d_in[1];
  float* y_out   = (float*)d_out;
  float* att_out = y_out + (size_t)Nn * Cc * HW;
  _Float16* whi = (_Float16*)d_ws;                  // 1.024 MB
  _Float16* wlo = whi + (size_t)Mm * Cc;            // 1.024 MB

  // contiguous zero-fill of att at full write BW (in-kernel scatter-zeroing was
  // the R5 bottleneck: 64B-chunk/4KB-stride writes ran at ~0.5 TB/s)
  hipMemsetAsync(att_out, 0, (size_t)Nn * Mm * HW * sizeof(float), stream);
  wcvt_kernel<<<(Mm * Cc + 255) / 256, 256, 0, stream>>>(w, whi, wlo);
  fused_mem_kernel<<<Tt / TB, 256, 0, stream>>>(x, w, whi, wlo, y_out, att_out);
}

// Round 2
// 567.485 us; speedup vs baseline: 1.6117x; 1.4921x over previous
//
#include <hip/hip_runtime.h>

typedef _Float16 f16x8 __attribute__((ext_vector_type(8)));
typedef float    f32x4 __attribute__((ext_vector_type(4)));

constexpr int Nn = 32, Cc = 256, HW = 1024, Mm = 2000, Tt = 32768;
constexpr int TB = 64;        // tokens per block (4 token-groups x 16)
constexpr int XROW = 264;     // X row stride (f16): 528 B rows -> natural bank swizzle
constexpr int YROW = 257;     // y accum row stride (fp32)
constexpr int LCAP = 2048;    // candidate cap (expected ~436/block, huge margin)
constexpr int NT = 63;        // M tiles of 32 rows (62 full + 16-row tail)
constexpr float LAMBDA = 0.0025f;
constexpr float PLO = LAMBDA * (1.0f - 3e-3f);   // borderline window (covers GEMM noise + Z regroup)
constexpr float PHI = LAMBDA * (1.0f + 3e-3f);
constexpr float ECUT = 4.8f;  // candidate cut (unchanged per-logit arithmetic -> same set)
constexpr float SCL = 4096.0f, ISCL = 1.0f / 4096.0f;

__global__ void wcvt_kernel(const float* __restrict__ w,
                            _Float16* __restrict__ whi, _Float16* __restrict__ wlo) {
  int i = blockIdx.x * 256 + threadIdx.x;
  if (i < Mm * Cc) {
    float v = w[i];
    _Float16 h = (_Float16)v;
    whi[i] = h;
    wlo[i] = (_Float16)((v - (float)h) * SCL);
  }
}

__device__ __forceinline__ void gl_lds16(const void* g, void* l) {
  __builtin_amdgcn_global_load_lds(
      (const __attribute__((address_space(1))) void*)g,
      (__attribute__((address_space(3))) void*)l, 16, 0, 0);
}

// TB=64 restructure: W tile (32 rows x 256 K, hi+lo = 32 KB) staged ONCE in LDS via
// global_load_lds double-buffer, consumed by 8 waves = 4 token-groups x 2 M-halves.
// W traffic/block drops 4x vs TB=16; compute per staged tile (~1300 cy/CU) >> load
// latency -> the 2-phase prefetch actually hides it (R1's reg-dbuf could not: depth-1
// with 300 cy compute vs ~700 cy L3 latency, and no VGPRs left for depth 3-4).
__global__ __launch_bounds__(512, 2)
void fused_mem_kernel(const float* __restrict__ x, const float* __restrict__ wgt,
                      const _Float16* __restrict__ whi, const _Float16* __restrict__ wlo,
                      float* __restrict__ y_out, float* __restrict__ att_out) {
  // region: X stage f16[64][264] x2 = 67584 B -> B dbuf 2x32768 B -> yL f32[64][257]
  __shared__ __align__(16) float bufB[TB * XROW];   // 67584 B
  __shared__ int   lm[LCAP];
  __shared__ float le[LCAP];
  __shared__ float la[LCAP];
  __shared__ float Zred[128];
  __shared__ float invZ[TB];
  __shared__ float l1s[TB];
  __shared__ float dens[TB];
  __shared__ int   lcnt;
  _Float16* Xh = (_Float16*)bufB;
  _Float16* Xl = Xh + TB * XROW;
  float*    yL = bufB;
  char*     Bb = (char*)bufB;

  const int tid = threadIdx.x;
  const int wv  = tid >> 6;                 // 0..7
  const int l   = tid & 63;
  const int qw  = l >> 4;
  const int lr  = l & 15;
  const int tg  = wv & 3;                   // token group (16 tokens)
  const int mh  = wv >> 2;                  // M half within 32-row tile
  const int t0  = blockIdx.x * TB;
  const int n   = t0 >> 10;
  const int hw0 = t0 & 1023;

  if (tid == 0) lcnt = 0;
  if (tid < TB) l1s[tid] = 0.f;

  // ---- phase 1: X tile (64 tokens x 256 c) -> LDS f16 hi/lo ----
  {
    const int h = tid & 63, cb = tid >> 6;
    const float* xp = x + ((size_t)n * Cc) * HW + hw0 + h;
    #pragma unroll
    for (int j = 0; j < 32; ++j) {
      int c = cb * 32 + j;
      float v = xp[(size_t)c * HW];          // 64 lanes consecutive: 256B chunks
      _Float16 hh = (_Float16)v;
      Xh[h * XROW + c] = hh;
      Xl[h * XROW + c] = (_Float16)((v - (float)hh) * SCL);
    }
  }
  __syncthreads();                                  // B1

  // A fragments (this wave's 16 tokens) -> regs; per-logit layout identical to R1
  f16x8 ahi[8], alo[8];
  #pragma unroll
  for (int ks = 0; ks < 8; ++ks) {
    ahi[ks] = *(const f16x8*)&Xh[(tg * 16 + lr) * XROW + ks * 32 + qw * 8];
    alo[ks] = *(const f16x8*)&Xl[(tg * 16 + lr) * XROW + ks * 32 + qw * 8];
  }
  __syncthreads();                                  // B1b: X region now free -> B dbuf

  // B staging: linear LDS dest, PRE-SWIZZLED global source (chunk ^= row&7) so the
  // swizzled ds_read below is conflict-minimal (512B rows alias banks otherwise).
  auto stage = [&](int b, int tile) {
    char* base = Bb + b * 32768;
    #pragma unroll
    for (int i = 0; i < 4; ++i) {
      const int bu = i * 512 + wv * 64;             // wave-uniform 16B-chunk base
      const int u2 = (bu + l) & 1023;
      const int row = u2 >> 5, chunk = u2 & 31;
      int mrow = tile * 32 + row; mrow = mrow < Mm ? mrow : (Mm - 1);  // tail clamp (unused rows)
      const char* src = (const char*)(i < 2 ? whi : wlo)
                      + (size_t)mrow * 512 + ((chunk ^ (row & 7)) << 4);
      gl_lds16(src, base + bu * 16);
    }
  };

  stage(0, 0);
  __syncthreads();                                  // B1c: tile0 landed (vmcnt drained)

  float zp[4] = {0.f, 0.f, 0.f, 0.f};
  const int rrow = mh * 16 + lr;                    // W row within 32-row tile
  const int rsw  = rrow & 7;
  int cur = 0;
  for (int t = 0; t < NT; ++t) {
    if (t + 1 < NT) stage(cur ^ 1, t + 1);          // prefetch flies under compute

    // att background zeroing (block-exclusive slice; replaces the ~260us hipMemset)
    {
      int m = t * 32 + (tid >> 4);
      if (m < Mm) {
        f32x4 z4 = {0.f, 0.f, 0.f, 0.f};
        *(f32x4*)(att_out + ((size_t)(n * Mm + m)) * HW + hw0 + ((tid & 15) << 2)) = z4;
      }
    }

    if (mh == 0 || t < NT - 1) {                    // tail tile has 16 valid rows
      const char* bb = Bb + cur * 32768;
      f16x8 bh[8], bl[8];
      #pragma unroll
      for (int ks = 0; ks < 8; ++ks) {
        const int ch = (((ks * 4 + qw) ^ rsw) << 4);
        bh[ks] = *(const f16x8*)(bb + rrow * 512 + ch);
        bl[ks] = *(const f16x8*)(bb + 16384 + rrow * 512 + ch);
      }
      f32x4 ahh = {0.f, 0.f, 0.f, 0.f};
      f32x4 axl = {0.f, 0.f, 0.f, 0.f};
      f32x4 alh = {0.f, 0.f, 0.f, 0.f};             // 3 independent 8-chains (ILP)
      #pragma unroll
      for (int ks = 0; ks < 8; ++ks) {
        ahh = __builtin_amdgcn_mfma_f32_16x16x32_f16(ahi[ks], bh[ks], ahh, 0, 0, 0);
        axl = __builtin_amdgcn_mfma_f32_16x16x32_f16(ahi[ks], bl[ks], axl, 0, 0, 0);
        alh = __builtin_amdgcn_mfma_f32_16x16x32_f16(alo[ks], bh[ks], alh, 0, 0, 0);
      }
      const int mrow_ = t * 32 + rrow;
      #pragma unroll
      for (int r = 0; r < 4; ++r) {
        float s = fmaf(axl[r] + alh[r], ISCL, ahh[r]);   // logit, bit-identical to R1
        float e = __expf(s);
        zp[r] += e;
        if (e > ECUT) {                                  // ~0.3% taken
          int slot = atomicAdd(&lcnt, 1);
          if (slot < LCAP) { lm[slot] = ((tg * 16 + qw * 4 + r) << 16) | mrow_; le[slot] = e; }
        }
      }
    }
    __syncthreads();                                // per-tile: 1 barrier, vmcnt drained here
    cur ^= 1;
  }

  #pragma unroll
  for (int o = 1; o < 16; o <<= 1)
    #pragma unroll
    for (int r = 0; r < 4; ++r) zp[r] += __shfl_xor(zp[r], o);
  if (lr == 0) {
    #pragma unroll
    for (int r = 0; r < 4; ++r) Zred[mh * 64 + tg * 16 + qw * 4 + r] = zp[r];
  }
  __syncthreads();                                  // B2

  if (tid < TB) invZ[tid] = 1.f / (Zred[tid] + Zred[64 + tid]);
  __syncthreads();                                  // B3

  // ---- phase 4: candidate scan (exact fp32 recompute of borderline) + L1 ----
  const int ne = min(lcnt, LCAP);
  for (int e = tid; e < ne; e += 512) {
    const int tm = lm[e];
    const int t = tm >> 16, m = tm & 0xFFFF;
    float p = le[e] * invZ[t];
    float a = 0.f;
    if (p > PLO) {
      float pu = p;
      if (p < PHI) {
        // borderline (~few per block): exact fp32 dot from global x, W
        const float* xr = x + ((size_t)n * Cc) * HW + hw0 + t;
        const float* wr = wgt + (size_t)m * Cc;
        float s = 0.f;
        for (int c = 0; c < Cc; ++c) s = fmaf(xr[(size_t)c * HW], wr[c], s);
        pu = expf(s) * invZ[t];
      }
      float d = pu - LAMBDA;
      if (d > 0.f) {
        a = (d * pu) / (d + 1e-12f);
        atomicAdd(&l1s[t], a);
      }
    }
    la[e] = a;
  }
  __syncthreads();                                  // B4

  if (tid < TB) dens[tid] = fmaxf(l1s[tid], 1e-12f);
  for (int i = tid; i < TB * YROW; i += 512) yL[i] = 0.f;   // B dbuf dead; alias reuse
  __syncthreads();                                  // B5

  // ---- phase 6: sparse GEMM2 from survivor list (fp32 W) + att scatter ----
  for (int e = wv; e < ne; e += 8) {                // wave-uniform entry -> no divergence
    float av = la[e];
    if (av > 0.f) {
      const int tm = lm[e];
      const int t = tm >> 16, m = tm & 0xFFFF;
      const float a = av / dens[t];
      float4 wf = *(const float4*)(wgt + (size_t)m * Cc + l * 4);
      atomicAdd(&yL[t * YROW + l * 4 + 0], a * wf.x);
      atomicAdd(&yL[t * YROW + l * 4 + 1], a * wf.y);
      atomicAdd(&yL[t * YROW + l * 4 + 2], a * wf.z);
      atomicAdd(&yL[t * YROW + l * 4 + 3], a * wf.w);
      if (l == 0)
        att_out[((size_t)(n * Mm + m)) * HW + hw0 + t] = a;   // bg zeroed in-loop above
    }
  }
  __syncthreads();                                  // B6

  // ---- phase 7: y write (256B chunks: 64 consecutive hw per c) ----
  {
    const int h = tid & 63, cb = tid >> 6;
    float* yp = y_out + ((size_t)n * Cc) * HW + hw0 + h;
    #pragma unroll
    for (int j = 0; j < 32; ++j) {
      int c = cb * 32 + j;
      yp[(size_t)c * HW] = yL[h * YROW + c];
    }
  }
}

extern "C" void kernel_launch(void* const* d_in, const int* in_sizes, int n_in,
                              void* d_out, int out_size, void* d_ws, size_t ws_size,
                              hipStream_t stream) {
  const float* x = (const float*)d_in[0];
  const float* w = (const float*)d_in[1];
  float* y_out   = (float*)d_out;
  float* att_out = y_out + (size_t)Nn * Cc * HW;
  _Float16* whi = (_Float16*)d_ws;                  // 1.024 MB
  _Float16* wlo = whi + (size_t)Mm * Cc;            // 1.024 MB

  // no hipMemsetAsync: att background is zeroed in-kernel (block-exclusive slices);
  // the 256MB memset was ~260us at ~1TB/s AND evicted W from L2 before GEMM1.
  wcvt_kernel<<<(Mm * Cc + 255) / 256, 256, 0, stream>>>(w, whi, wlo);
  fused_mem_kernel<<<Tt / TB, 512, 0, stream>>>(x, w, whi, wlo, y_out, att_out);
}